// Round 7
// baseline (1521.108 us; speedup 1.0000x reference)
//
#include <hip/hip_runtime.h>
#include <math.h>

// DiffDispatchLP: batched (256x) PDHG, 400 iters, one WG (16 waves, 1024 thr)
// per item. Phase B row-tasks atomically accumulate pre-scaled contributions
// into ONE combo slot per column (stride-1, conflict-free); phase A = 1-2
// reads + zero + x_bar write. 16 waves -> every row family gets whole waves
// (no divergent doubling) and 4 waves/SIMD hide LDS latency.
//
// S layout (dwords), regions of 104 = [4 front guard][96 data][4 back guard]:
//  R0 c_bar   data 4+t      R1 d_bar  data 108+t   R2 yc_bar data 212+t
//  R3 yd_bar  data 316+t    R4 s_bar  data 420+t
//  R5 CC combo 524+t        R6 DC 628+t            R7 YCC 732+t
//  R8 YDC 836+t             R9 SC 940+t
//  TC slot 1040, RED 1044..1059. Guards are never read (or provably 0).

#define NITER 400
#define PITER 10
#define STOT 1060

__global__ __launch_bounds__(1024, 1)
void lp_solve_kernel(const float* __restrict__ price, float* __restrict__ out) {
  __shared__ float S[STOT];

  const int tid = threadIdx.x, lane = tid & 63, wid = tid >> 6, bi = blockIdx.x;
  const double ETA_D = sqrt(0.91);
  const float cET = (float)(-(ETA_D * 0.25));  // -ETA*DT
  const float cDE = (float)(0.25 / ETA_D);     // DT/ETA

  // ============ phase A per-thread constants (one column per thread) ============
  const bool colAct = (tid < 480);
  const int colv = colAct ? tid : 479;
  const int vty = colv / 96;            // 0 c, 1 d, 2 yc, 3 yd, 4 soc
  const int t = colv - 96 * vty;
  const int aCmb = 524 + 104 * vty + t; // combo slot (read + zero)
  const int aXw  = 4   + 104 * vty + t; // x_bar write slot
  const float ctc = (vty == 0) ? 0.25f : 0.f;

  // ============ phase B per-thread constants ============
  // BOX: w8 t=0..63; w9 lanes<32 t=64..95
  const bool roleBox = (wid == 8) || (wid == 9 && lane < 32);
  const bool boxWave = (wid == 8) || (wid == 9);
  const int tb = (wid == 8) ? lane : (64 + (lane & 31));
  // MD: w10 i=0..63, w11 i=64..127, w12 i=128..189 (lanes<62)
  const bool mdWave = (wid >= 10) && (wid <= 12);
  const bool roleMd = (wid == 10) || (wid == 11) || (wid == 12 && lane < 62);
  const int mdi = (wid == 10) ? lane : (wid == 11) ? (64 + lane)
                                                   : (128 + ((lane < 62) ? lane : 61));
  const int mv = (mdi >= 95) ? 1 : 0;
  const int mt = mdi - 95 * mv;
  const int mdR = (mv ? 316 : 212) + mt;   // x_bar reads mdR-1 .. mdR+3
  const int mdW = (mv ? 836 : 732) + mt;   // combo writes mdW-1 .. mdW+3
  const float cv2 = (mt <= 93) ? 1.f : 0.f;
  const float cv3 = (mt <= 92) ? 1.f : 0.f;
  // RAMP: w13 rt=1..64; w14 lanes<31 rt=65..95
  const bool rampWave = (wid == 13) || (wid == 14);
  const bool roleRamp = (wid == 13) || (wid == 14 && lane < 31);
  const int rt = (wid == 13) ? (1 + lane) : (65 + ((lane < 31) ? lane : 30));
  // SW: w15 st=0..63; w7 lanes<31 st=64..94
  const bool swWave = (wid == 15) || (wid == 7);
  const bool roleSw = (wid == 15) || (wid == 7 && lane < 31);
  const int st = (wid == 15) ? lane : (64 + ((lane < 31) ? lane : 30));
  // EQ: w6 er=0..63; w4 lanes<33 er=64..96
  const bool eqWave = (wid == 6) || (wid == 4);
  const bool roleEq = (wid == 6) || (wid == 4 && lane < 33);
  const int er = (wid == 6) ? lane : (64 + ((lane < 33) ? lane : 32));
  const float cEb = (er == 96) ? -1.f : 1.f;
  const int aEqC  = (er <= 95) ? (524 + er) : 620;   // guard for row 96
  const int aEqD  = (er <= 95) ? (628 + er) : 724;
  const int aEqSp = 940 + ((er <= 95) ? er : 95);    // row 96 hits s_95
  const int aEqSm = (er <= 95) ? (939 + er) : 1036;  // er=0 -> front guard

  // ============ state ============
  float xA = 0.f, qA = 0.f;
  float yb0=0,yb1=0,yb2=0,yb3=0,yb4=0,yb5=0,yb6=0,yb7=0,yb8=0,yb9=0,yb10=0,yb11=0,yb12=0;
  float ym1=0, ym2=0, ym3=0, yr0=0, yr1=0, yr2=0, yr3=0, ysw0=0, ysw1=0, yeq=0, ytc=0;
  float sigv = 0.f;

  auto phaseB = [&](bool power) {
    const float sig = sigv;
    if (boxWave) {  // 13 rows at tb -> 5 combo contributions
      float c_  = S[4 + tb],   d_  = S[108 + tb];
      float yc_ = S[212 + tb], yd_ = S[316 + tb];
      float s_  = S[420 + tb];
      float v0,v1,v2,v3,v4,v5,v6,v7,v8,v9,v10,v11,v12;
      if (power) {
        v0=c_; v1=d_; v2=-c_; v3=-d_; v4=-yc_; v5=yc_; v6=-yd_; v7=yd_;
        v8=-s_; v9=s_; v10=yc_+yd_; v11=c_-195.f*yc_; v12=d_-195.f*yd_;
      } else {
        yb0  = fmaxf(yb0  + sig*(c_  - 195.f), 0.f);      v0 = yb0;
        yb1  = fmaxf(yb1  + sig*(d_  - 195.f), 0.f);      v1 = yb1;
        yb2  = fmaxf(yb2  - sig*c_,            0.f);      v2 = yb2;
        yb3  = fmaxf(yb3  - sig*d_,            0.f);      v3 = yb3;
        yb4  = fmaxf(yb4  - sig*yc_,           0.f);      v4 = yb4;
        yb5  = fmaxf(yb5  + sig*(yc_ - 1.f),   0.f);      v5 = yb5;
        yb6  = fmaxf(yb6  - sig*yd_,           0.f);      v6 = yb6;
        yb7  = fmaxf(yb7  + sig*(yd_ - 1.f),   0.f);      v7 = yb7;
        yb8  = fmaxf(yb8  - sig*s_,            0.f);      v8 = yb8;
        yb9  = fmaxf(yb9  + sig*(s_ - 800.f),  0.f);      v9 = yb9;
        yb10 = fmaxf(yb10 + sig*(yc_ + yd_ - 1.f), 0.f);  v10 = yb10;
        yb11 = fmaxf(yb11 + sig*(c_ - 195.f*yc_), 0.f);   v11 = yb11;
        yb12 = fmaxf(yb12 + sig*(d_ - 195.f*yd_), 0.f);   v12 = yb12;
      }
      if (roleBox) {
        atomicAdd(&S[524 + tb], v0 - v2 + v11);
        atomicAdd(&S[628 + tb], v1 - v3 + v12);
        atomicAdd(&S[732 + tb], -v4 + v5 + v10 - 195.f * v11);
        atomicAdd(&S[836 + tb], -v6 + v7 + v10 - 195.f * v12);
        atomicAdd(&S[940 + tb], -v8 + v9);
      }
    }
    if (mdWave) {  // min-duration: 3 rows at (mv,mt)
      float mp  = S[mdR - 1];
      float mc  = S[mdR],     m1v = S[mdR + 1];
      float m2v = S[mdR + 2], m3v = S[mdR + 3];
      float base = mc - mp;
      float d1 = base - m1v, d2 = base - m2v, d3 = base - m3v;
      float o1, o2, o3;
      if (power) { o1 = d1; o2 = d2; o3 = d3; }
      else {
        ym1 = fmaxf(ym1 + sig * d1, 0.f); o1 = ym1;
        ym2 = fmaxf(ym2 + sig * d2, 0.f); o2 = ym2;
        ym3 = fmaxf(ym3 + sig * d3, 0.f); o3 = ym3;
      }
      if (roleMd) {
        float ms = o1 + cv2 * o2 + cv3 * o3;
        atomicAdd(&S[mdW],     ms);
        atomicAdd(&S[mdW - 1], -ms);
        atomicAdd(&S[mdW + 1], -o1);
        atomicAdd(&S[mdW + 2], -cv2 * o2);
        atomicAdd(&S[mdW + 3], -cv3 * o3);
      }
    }
    if (rampWave) {  // 4 rows at rt -> 2 combos x 2 slots
      float rcm = S[3 + rt],   rc0 = S[4 + rt];
      float rdm = S[107 + rt], rd0 = S[108 + rt];
      float u0, u1, u2, u3;
      if (power) { u0 = rc0 - rcm; u1 = rcm - rc0; u2 = rd0 - rdm; u3 = rdm - rd0; }
      else {
        yr0 = fmaxf(yr0 + sig * (rc0 - rcm - 65.f), 0.f); u0 = yr0;
        yr1 = fmaxf(yr1 + sig * (rcm - rc0 - 65.f), 0.f); u1 = yr1;
        yr2 = fmaxf(yr2 + sig * (rd0 - rdm - 65.f), 0.f); u2 = yr2;
        yr3 = fmaxf(yr3 + sig * (rdm - rd0 - 65.f), 0.f); u3 = yr3;
      }
      if (roleRamp) {
        float uc = u0 - u1, ud = u2 - u3;
        atomicAdd(&S[524 + rt], uc);
        atomicAdd(&S[523 + rt], -uc);
        atomicAdd(&S[628 + rt], ud);
        atomicAdd(&S[627 + rt], -ud);
      }
    }
    if (swWave) {  // 2 rows at st
      float a0 = S[212 + st], a1 = S[213 + st];
      float b0 = S[316 + st], b1 = S[317 + st];
      float p0, p1;
      if (power) { p0 = a0 + b1; p1 = b0 + a1; }
      else {
        ysw0 = fmaxf(ysw0 + sig * (a0 + b1 - 1.f), 0.f); p0 = ysw0;
        ysw1 = fmaxf(ysw1 + sig * (b0 + a1 - 1.f), 0.f); p1 = ysw1;
      }
      if (roleSw) {
        atomicAdd(&S[732 + st], p0);
        atomicAdd(&S[837 + st], p0);
        atomicAdd(&S[836 + st], p1);
        atomicAdd(&S[733 + st], p1);
      }
    }
    if (eqWave) {  // equality row er (free dual); er=96 via guards + cEb
      float sp = S[419 + er], sc = S[420 + er];
      float xc = S[4 + er],   xd = S[108 + er];
      float dot = sc - cEb * sp + cET * xc + cDE * xd;
      float ev;
      if (power) ev = dot;
      else { yeq += sig * dot; ev = yeq; }
      if (roleEq) {
        atomicAdd(&S[aEqC],  cET * ev);
        atomicAdd(&S[aEqD],  cDE * ev);
        atomicAdd(&S[aEqSp], ev);
        atomicAdd(&S[aEqSm], -ev);
      }
    }
    if (wid == 5) {  // total-charge: 0.25 * sum(c_bar) <= 1200
      float ssum = S[4 + lane] + ((lane < 32) ? S[68 + lane] : 0.f);
#pragma unroll
      for (int m = 32; m >= 1; m >>= 1) ssum += __shfl_xor(ssum, m, 64);
      if (lane == 0) {
        float wv;
        if (power) wv = 0.25f * ssum;
        else { ytc = fmaxf(ytc + sig * (0.25f * ssum - 1200.f), 0.f); wv = ytc; }
        S[1040] = wv;
      }
    }
  };

  // ============ power iteration: ||K||_2 ============
  for (int i = tid; i < STOT; i += 1024) S[i] = 0.f;
  __syncthreads();
  if (colAct) S[aXw] = 1.f;
  __syncthreads();

  float lam2 = 1.f;
  for (int pit = 0; pit < PITER; ++pit) {
    phaseB(true);                       // combos += K v (pre-combined)
    __syncthreads();
    float gA = 0.f;
    if (colAct) {
      gA = S[aCmb] + ctc * S[1040];     // (K^T K v)[col]
      S[aCmb] = 0.f;
    }
    float part = gA * gA;
#pragma unroll
    for (int m = 32; m >= 1; m >>= 1) part += __shfl_xor(part, m, 64);
    if (lane == 0) S[1044 + wid] = part;
    __syncthreads();
    float nrm = 0.f;
#pragma unroll
    for (int w = 0; w < 16; ++w) nrm += S[1044 + w];
    lam2 = sqrtf(nrm);
    float inv = 1.f / lam2;
    if (colAct) S[aXw] = gA * inv;
    __syncthreads();
  }
  const float tauv = (float)(0.9 / sqrt((double)lam2));
  sigv = tauv;

  // ============ PDHG init ============
  if (tid == 0) S[1040] = 0.f;          // tc dual starts 0
  if (tid < 96)       qA =  0.25f * price[bi * 96 + tid];
  else if (tid < 192) qA = -0.25f * price[bi * 96 + (tid - 96)];
  __syncthreads();

  // ============ 400 PDHG iterations ============
#pragma unroll 1
  for (int it = 0; it < NITER; ++it) {
    if (colAct) {
      float g = S[aCmb] + ctc * S[1040];
      S[aCmb] = 0.f;
      float xa = xA - tauv * (qA + g);
      S[aXw] = 2.f * xa - xA;
      xA = xa;
    }
    __syncthreads();
    phaseB(false);
    __syncthreads();
  }

  // output: c then d, each (256,96)
  if (tid < 96)       out[bi * 96 + tid] = xA;
  else if (tid < 192) out[24576 + bi * 96 + (tid - 96)] = xA;
}

extern "C" void kernel_launch(void* const* d_in, const int* in_sizes, int n_in,
                              void* d_out, int out_size, void* d_ws, size_t ws_size,
                              hipStream_t stream) {
  const float* price = (const float*)d_in[0];
  float* outp = (float*)d_out;
  hipLaunchKernelGGL(lp_solve_kernel, dim3(256), dim3(1024), 0, stream, price, outp);
}

// Round 8
// 317.595 us; speedup vs baseline: 4.7895x; 4.7895x over previous
//
#include <hip/hip_runtime.h>
#include <math.h>

// DiffDispatchLP: batched (256x) PDHG, 400 iters, one WG (16 waves, 1024 thr)
// per item. R5's disjoint-plane stride-1 LDS layout + plain writes (no
// atomics), spread over 16 waves so each wave runs ONE uniform task body
// (max ~11 LDS instr) and 4 waves/SIMD hide ds_read latency.
//
// sy layout (dwords), regions of 104 = [4 guard][data][guards]:
//   VB[v] at 624v: MD1@0 MD2@104 MD3@208 MS@312 BY@416 SW@520   (v=0,1)
//   EQ@1248  BS@1352  BCD (c@1456,d@1560)  UC (uc@1664,ud@1768)  TC@1872
// sxb: C@0 D@104 YC@208 YD@312 S@416  (slot = region + 4 + t)

#define NITER 400
#define PITER 10
#define NY 1874
#define NX 520

__global__ __launch_bounds__(1024, 1)
void lp_solve_kernel(const float* __restrict__ price, float* __restrict__ out) {
  __shared__ float sy[NY];
  __shared__ float sxb[NX];
  __shared__ float s_red[16];

  const int tid = threadIdx.x, lane = tid & 63, wid = tid >> 6, bi = blockIdx.x;
  const double ETA_D = sqrt(0.91);
  const float cET = (float)(-(ETA_D * 0.25));  // -ETA*DT
  const float cDE = (float)(0.25 / ETA_D);     // DT/ETA

  // ================= phase A per-thread constants (wid 0..7) =================
  const bool colAct = (tid < 480);
  const int col = colAct ? tid : 479;
  const int vty = col / 96;            // 0 c, 1 d, 2 yc, 3 yd, 4 soc
  const int t = col - 96 * vty;
  const int wX = 104 * vty + 4 + t;    // x_bar write slot
  // cd body (wid 0..2)
  const int v01 = vty & 1;
  const int aBC = 1460 + 104 * v01 + t;
  const int aEQ = 1252 + t;
  const int aUM = 1667 + 104 * v01 + t;
  const float ce = v01 ? cDE : cET;
  const float ctc = v01 ? 0.f : 0.25f;
  // y body (wid 3..5)
  const int yv = (vty >= 2) ? (vty - 2) : 0;
  const int bv = 624 * yv + t;
  const int bw = 624 * (1 - yv) + t;
  // soc body (wid 6..7)
  const float ce1 = (t <= 94) ? -1.f : 1.f;
  const int aBS = 1356 + t;

  // ================= phase B per-thread constants =================
  // BOX: w8 t=0..63; w9 lanes<32 t=64..95
  const bool boxRun = (wid == 8) || (wid == 9);
  const bool boxAct = (wid == 8) || (wid == 9 && lane < 32);
  const int tb = (wid == 8) ? lane : (64 + (lane & 31));
  // MD: w10 i=0..63, w11 i=64..127, w12 i=128..189 (lanes<62)
  const bool mdRun = (wid >= 10) && (wid <= 12);
  const bool mdAct = mdRun && !(wid == 12 && lane >= 62);
  const int mi = (wid == 10) ? lane
               : (wid == 11) ? (64 + lane)
                             : (128 + ((lane < 62) ? lane : 61));
  const int mv = (mi >= 95) ? 1 : 0;
  const int mt = mi - 95 * mv;
  const int mx = 104 * (2 + mv) + mt;   // sxb y_v base (reads mx+3 .. mx+7)
  const int mw = 624 * mv + mt;         // sy VB[v] write base
  const float cv2 = (mt <= 93) ? 1.f : 0.f;
  const float cv3 = (mt <= 92) ? 1.f : 0.f;
  // RAMP: w13 rt=1..64; w14 lanes<31 rt=65..95
  const bool rRun = (wid == 13) || (wid == 14);
  const bool rAct = (wid == 13) || (wid == 14 && lane < 31);
  const int rt = (wid == 13) ? (1 + lane) : (65 + ((lane < 31) ? lane : 30));
  // SW: w15 st=0..63; w14 lanes<31 st=64..94
  const bool sRun = (wid == 15) || (wid == 14);
  const bool sAct = (wid == 15) || (wid == 14 && lane < 31);
  const int st = (wid == 15) ? lane : (64 + ((lane < 31) ? lane : 30));
  // EQ: w6 er=0..63; w7 lanes<33 er=64..96
  const bool eqRun = (wid == 6) || (wid == 7);
  const bool eqAct = (wid == 6) || (wid == 7 && lane < 33);
  const int er = (wid == 6) ? lane : (64 + ((lane < 33) ? lane : 32));
  const float cEb = (er == 96) ? -1.f : 1.f;

  // ================= state =================
  float xA = 0.f, qA = 0.f;
  float yb0=0,yb1=0,yb2=0,yb3=0,yb4=0,yb5=0,yb6=0,yb7=0,yb8=0,yb9=0,yb10=0,yb11=0,yb12=0;
  float ym1=0, ym2=0, ym3=0, yr0=0, yr1=0, yr2=0, yr3=0, ysw0=0, ysw1=0, yeq=0, ytc=0;
  float sigv = 0.f;

  auto gatherA = [&]() -> float {
    if (wid < 3) {
      float b = sy[aBC], e = sy[aEQ];
      float um = sy[aUM], up = sy[aUM + 1];
      float tc = sy[1872];
      return b + ce * e + um - up + ctc * tc;
    } else if (wid < 6) {
      float k1 = sy[bv + 3], k2 = sy[bv + 106], k3 = sy[bv + 209];
      float m0 = sy[bv + 316], m1 = sy[bv + 317];
      float bY = sy[bv + 420], s0 = sy[bv + 524], s1 = sy[bw + 523];
      return bY + s0 + s1 + (m0 - m1) - (k1 + k2 + k3);
    } else {
      float e0 = sy[aEQ], e1 = sy[aEQ + 1], bS = sy[aBS];
      return bS + e0 + ce1 * e1;
    }
  };

  auto phaseB = [&](bool power) {
    const float sig = sigv;
    if (boxRun) {  // BOX: 13 rows at tb -> 5 combos
      float c_ = sxb[4 + tb], d_ = sxb[108 + tb];
      float yc_ = sxb[212 + tb], yd_ = sxb[316 + tb], s_ = sxb[420 + tb];
      float v0,v1,v2,v3,v4,v5,v6,v7,v8,v9,v10,v11,v12;
      if (power) {
        v0=c_; v1=d_; v2=-c_; v3=-d_; v4=-yc_; v5=yc_; v6=-yd_; v7=yd_;
        v8=-s_; v9=s_; v10=yc_+yd_; v11=c_-195.f*yc_; v12=d_-195.f*yd_;
      } else {
        yb0  = fmaxf(yb0  + sig*(c_  - 195.f), 0.f);      v0 = yb0;
        yb1  = fmaxf(yb1  + sig*(d_  - 195.f), 0.f);      v1 = yb1;
        yb2  = fmaxf(yb2  - sig*c_,            0.f);      v2 = yb2;
        yb3  = fmaxf(yb3  - sig*d_,            0.f);      v3 = yb3;
        yb4  = fmaxf(yb4  - sig*yc_,           0.f);      v4 = yb4;
        yb5  = fmaxf(yb5  + sig*(yc_ - 1.f),   0.f);      v5 = yb5;
        yb6  = fmaxf(yb6  - sig*yd_,           0.f);      v6 = yb6;
        yb7  = fmaxf(yb7  + sig*(yd_ - 1.f),   0.f);      v7 = yb7;
        yb8  = fmaxf(yb8  - sig*s_,            0.f);      v8 = yb8;
        yb9  = fmaxf(yb9  + sig*(s_ - 800.f),  0.f);      v9 = yb9;
        yb10 = fmaxf(yb10 + sig*(yc_ + yd_ - 1.f), 0.f);  v10 = yb10;
        yb11 = fmaxf(yb11 + sig*(c_ - 195.f*yc_), 0.f);   v11 = yb11;
        yb12 = fmaxf(yb12 + sig*(d_ - 195.f*yd_), 0.f);   v12 = yb12;
      }
      if (boxAct) {
        sy[1460 + tb] = v0 - v2 + v11;                     // bC
        sy[1564 + tb] = v1 - v3 + v12;                     // bD
        sy[420 + tb]  = -v4 + v5 + v10 - 195.f * v11;      // bYC
        sy[1044 + tb] = -v6 + v7 + v10 - 195.f * v12;      // bYD
        sy[1356 + tb] = -v8 + v9;                          // bS
      }
    }
    if (mdRun) {  // MIN-DURATION: rows (mv, k=1..3, mt) + own-sum
      float mp = sxb[mx + 3];                // y_v[mt-1] (guard at mt=0)
      float mc = sxb[mx + 4], m1v = sxb[mx + 5];
      float m2v = sxb[mx + 6], m3v = sxb[mx + 7];
      float base = mc - mp;
      float d1 = base - m1v, d2 = base - m2v, d3 = base - m3v;
      float o1, o2, o3;
      if (power) { o1 = d1; o2 = d2; o3 = d3; }
      else {
        ym1 = fmaxf(ym1 + sig * d1, 0.f); o1 = ym1;
        ym2 = fmaxf(ym2 + sig * d2, 0.f); o2 = ym2;
        ym3 = fmaxf(ym3 + sig * d3, 0.f); o3 = ym3;
      }
      if (mdAct) {
        sy[mw + 4]   = o1;                        // MD1[mt]
        sy[mw + 108] = o2;                        // MD2[mt]
        sy[mw + 212] = o3;                        // MD3[mt]
        sy[mw + 316] = o1 + cv2 * o2 + cv3 * o3;  // MS[mt]
      }
    }
    if (rRun) {  // RAMP: 4 rows -> 2 combos
      float rcm = sxb[3 + rt], rc0 = sxb[4 + rt];
      float rdm = sxb[107 + rt], rd0 = sxb[108 + rt];
      float u0, u1, u2, u3;
      if (power) { u0 = rc0 - rcm; u1 = rcm - rc0; u2 = rd0 - rdm; u3 = rdm - rd0; }
      else {
        yr0 = fmaxf(yr0 + sig * (rc0 - rcm - 65.f), 0.f); u0 = yr0;
        yr1 = fmaxf(yr1 + sig * (rcm - rc0 - 65.f), 0.f); u1 = yr1;
        yr2 = fmaxf(yr2 + sig * (rd0 - rdm - 65.f), 0.f); u2 = yr2;
        yr3 = fmaxf(yr3 + sig * (rdm - rd0 - 65.f), 0.f); u3 = yr3;
      }
      if (rAct) { sy[1667 + rt] = u0 - u1; sy[1771 + rt] = u2 - u3; }
    }
    if (sRun) {  // SWITCH: 2 raw rows
      float a0 = sxb[212 + st], a1 = sxb[213 + st];
      float b0 = sxb[316 + st], b1 = sxb[317 + st];
      float p0, p1;
      if (power) { p0 = a0 + b1; p1 = b0 + a1; }
      else {
        ysw0 = fmaxf(ysw0 + sig * (a0 + b1 - 1.f), 0.f); p0 = ysw0;
        ysw1 = fmaxf(ysw1 + sig * (b0 + a1 - 1.f), 0.f); p1 = ysw1;
      }
      if (sAct) { sy[524 + st] = p0; sy[1148 + st] = p1; }
    }
    if (eqRun) {  // EQUALITY (free dual); r=96 via guards + cEb=-1
      float ep = sxb[419 + er], ecur = sxb[420 + er];
      float exc = sxb[4 + er], exd = sxb[108 + er];
      float dot = ecur - cEb * ep + cET * exc + cDE * exd;
      float ev;
      if (power) ev = dot;
      else { yeq += sig * dot; ev = yeq; }
      if (eqAct) sy[1252 + er] = ev;
    }
    if (wid == 15) {  // TOTAL-CHARGE: 0.25 * sum(c_bar) <= 1200
      float ssum = sxb[4 + lane] + ((lane < 32) ? sxb[68 + lane] : 0.f);
#pragma unroll
      for (int m = 32; m >= 1; m >>= 1) ssum += __shfl_xor(ssum, m, 64);
      if (lane == 0) {
        float wv;
        if (power) wv = 0.25f * ssum;
        else { ytc = fmaxf(ytc + sig * (0.25f * ssum - 1200.f), 0.f); wv = ytc; }
        sy[1872] = wv;
      }
    }
  };

  // ================= power iteration: ||K||_2 =================
  for (int i = tid; i < NY; i += 1024) sy[i] = 0.f;
  for (int i = tid; i < NX; i += 1024) sxb[i] = 0.f;
  __syncthreads();
  if (colAct) sxb[wX] = 1.f;
  __syncthreads();

  float lam2 = 1.f;
  for (int pit = 0; pit < PITER; ++pit) {
    phaseB(true);                      // sy = combined(K v)
    __syncthreads();
    float gA = 0.f;
    if (wid < 8) {
      gA = gatherA();                  // (K^T K v) per column
      if (!colAct) gA = 0.f;
    }
    float part = gA * gA;
#pragma unroll
    for (int m = 32; m >= 1; m >>= 1) part += __shfl_xor(part, m, 64);
    if (lane == 0) s_red[wid] = part;
    __syncthreads();
    float nrm = 0.f;
#pragma unroll
    for (int w = 0; w < 16; ++w) nrm += s_red[w];
    lam2 = sqrtf(nrm);
    float inv = 1.f / lam2;
    if (colAct) sxb[wX] = gA * inv;
    __syncthreads();
  }
  const float tauv = (float)(0.9 / sqrt((double)lam2));
  sigv = tauv;

  // ================= PDHG =================
  __syncthreads();
  for (int i = tid; i < NY; i += 1024) sy[i] = 0.f;
  if (tid < 96)       qA =  0.25f * price[bi * 96 + tid];
  else if (tid < 192) qA = -0.25f * price[bi * 96 + (tid - 96)];
  __syncthreads();

#pragma unroll 1
  for (int it = 0; it < NITER; ++it) {
    if (wid < 8) {
      float gA = gatherA();
      if (colAct) {
        float xa = xA - tauv * (qA + gA);
        sxb[wX] = 2.f * xa - xA;
        xA = xa;
      }
    }
    __syncthreads();
    phaseB(false);
    __syncthreads();
  }

  // output: c then d, each (256,96)
  if (tid < 96)       out[bi * 96 + tid] = xA;
  else if (tid < 192) out[24576 + bi * 96 + (tid - 96)] = xA;
}

extern "C" void kernel_launch(void* const* d_in, const int* in_sizes, int n_in,
                              void* d_out, int out_size, void* d_ws, size_t ws_size,
                              hipStream_t stream) {
  const float* price = (const float*)d_in[0];
  float* outp = (float*)d_out;
  hipLaunchKernelGGL(lp_solve_kernel, dim3(256), dim3(1024), 0, stream, price, outp);
}